// Round 17
// baseline (132.768 us; speedup 1.0000x reference)
//
#include <hip/hip_runtime.h>
#include <hip/hip_bf16.h>

#define NEG_SLOPE 0.2f
#define EPB 4096    // edges per block in bucket_scatter (256 thr x 16)
#define NHB 64      // hist blocks
#define NBUK 1024   // bucket slots (bucket = node >> 6, 64 nodes/bucket)

typedef __attribute__((ext_vector_type(8))) short short8v;   // 8 bf16 bit-patterns
typedef __attribute__((ext_vector_type(4))) float f32x4;

__device__ inline float blo(unsigned u) { return __uint_as_float(u << 16); }
__device__ inline float bhi(unsigned u) { return __uint_as_float(u & 0xffff0000u); }
__device__ inline unsigned short bf16bits(float f) {
    __hip_bfloat16 b = __float2bfloat16(f);
    return *(unsigned short*)&b;
}
__device__ inline unsigned pack2bf(float e, float o) {
    return ((unsigned)bf16bits(o) << 16) | (unsigned)bf16bits(e);
}

// ---------------------------------------------------------------------------
// Augmented transposed weights Wt[80][K] bf16:
// j<64 -> W_src[k][j]; j=64 -> W_src@a_src; j=65 -> W_dst@a_dst; 66..79 -> 0.
// ---------------------------------------------------------------------------
template <int K>
__device__ inline void build_wt(unsigned short* __restrict__ Wt,
                                const float* __restrict__ W_src,
                                const float* __restrict__ a_src,
                                const float* __restrict__ W_dst,
                                const float* __restrict__ a_dst, int tid) {
    for (int i = tid; i < 64 * K; i += 256) {
        int k = i >> 6, j = i & 63;
        Wt[j * K + k] = bf16bits(W_src[i]);
    }
    for (int i = tid; i < 2 * K; i += 256) {
        int which = (i >= K) ? 1 : 0;
        int k = i - which * K;
        const float* Wr = (which ? W_dst : W_src) + k * 64;
        const float* av = which ? a_dst : a_src;
        float s = 0.f;
        #pragma unroll
        for (int j = 0; j < 64; ++j) s += Wr[j] * av[j];
        Wt[(64 + which) * K + k] = bf16bits(s);
    }
    for (int i = tid; i < 14 * K; i += 256) Wt[66 * K + i] = 0;
}

// ---------------------------------------------------------------------------
// prep: blocks 0..NHB-1 = 1024-bucket histogram partials; NHB = Wt1; NHB+1 = Wt2.
// ---------------------------------------------------------------------------
__global__ __launch_bounds__(256) void prep(
    const int* __restrict__ dst, int* __restrict__ partials, int E,
    const float* __restrict__ W1_src, const float* __restrict__ a1_src,
    const float* __restrict__ W1_dst, const float* __restrict__ a1_dst,
    const float* __restrict__ W2_src, const float* __restrict__ a2_src,
    const float* __restrict__ W2_dst, const float* __restrict__ a2_dst,
    unsigned short* __restrict__ Wt1, unsigned short* __restrict__ Wt2) {
    __shared__ int lh[NBUK];
    int tid = threadIdx.x, b = blockIdx.x;
    if (b < NHB) {
        for (int s = tid; s < NBUK; s += 256) lh[s] = 0;
        __syncthreads();
        for (int e = b * 256 + tid; e < E; e += NHB * 256)
            atomicAdd(&lh[dst[e] >> 6], 1);
        __syncthreads();
        for (int s = tid; s < NBUK; s += 256)
            partials[b * NBUK + s] = lh[s];
    } else if (b == NHB) {
        build_wt<128>(Wt1, W1_src, a1_src, W1_dst, a1_dst, tid);
    } else {
        build_wt<64>(Wt2, W2_src, a2_src, W2_dst, a2_dst, tid);
    }
}

// ---------------------------------------------------------------------------
// scan1024 (1 block): reduce hist partials -> exclusive scan -> bucket_base;
// zero the cursors. Thread owns 4 consecutive slots (int4 loads).
// ---------------------------------------------------------------------------
__global__ __launch_bounds__(256) void scan1024(const int* __restrict__ partials,
                                                int* __restrict__ bucket_base,
                                                int* __restrict__ cursor0) {
    __shared__ int tsum[256];
    int tid = threadIdx.x;
    int4 v = make_int4(0, 0, 0, 0);
    for (int b = 0; b < NHB; ++b) {
        int4 p = *(const int4*)&partials[b * NBUK + 4 * tid];
        v.x += p.x; v.y += p.y; v.z += p.z; v.w += p.w;
    }
    int t = v.x + v.y + v.z + v.w;
    tsum[tid] = t;
    __syncthreads();
    for (int off = 1; off < 256; off <<= 1) {
        int u = (tid >= off) ? tsum[tid - off] : 0;
        __syncthreads();
        tsum[tid] += u;
        __syncthreads();
    }
    int base = tsum[tid] - t;    // exclusive across thread groups
    bucket_base[4 * tid + 0] = base;
    bucket_base[4 * tid + 1] = base + v.x;
    bucket_base[4 * tid + 2] = base + v.x + v.y;
    bucket_base[4 * tid + 3] = base + v.x + v.y + v.z;
    if (tid == 255) bucket_base[NBUK] = tsum[255];   // == E
    *(int4*)&cursor0[4 * tid] = make_int4(0, 0, 0, 0);
}

// ---------------------------------------------------------------------------
// NT body (register-resident, no LDS): wave = 16-row x 80-col tile.
//   h = x@W_src (packed bf16 [N][32]), alpha_src = col 64, alpha_dst = col 65.
// ---------------------------------------------------------------------------
template <int K, bool INBF16>
__device__ inline void nt_body(int nb, const void* __restrict__ x_,
                               const unsigned short* __restrict__ Wt,
                               unsigned* __restrict__ hb_out,
                               float* __restrict__ alpha_src,
                               float* __restrict__ alpha_dst, int N, int tid) {
    int wid = tid >> 6, l = tid & 63;
    int rowbase = (nb * 4 + wid) * 16;
    if (rowbase >= N) return;
    int jcol = l & 15, kg = (l >> 4) * 8;

    int r = rowbase + jcol;
    if (r >= N) r = N - 1;           // clamp; stores guarded
    const float*          xr32 = (const float*)x_ + (size_t)r * K + kg;
    const unsigned short* xr16 = (const unsigned short*)x_ + (size_t)r * K + kg;

    f32x4 acc[5];
    #pragma unroll
    for (int t = 0; t < 5; ++t) acc[t] = (f32x4){0.f, 0.f, 0.f, 0.f};

    #pragma unroll
    for (int kt = 0; kt < K / 32; ++kt) {
        short8v a;
        if constexpr (INBF16) {
            a = *(const short8v*)(xr16 + kt * 32);
        } else {
            float4 xa = *(const float4*)(xr32 + kt * 32);
            float4 xb = *(const float4*)(xr32 + kt * 32 + 4);
            a[0] = (short)bf16bits(xa.x); a[1] = (short)bf16bits(xa.y);
            a[2] = (short)bf16bits(xa.z); a[3] = (short)bf16bits(xa.w);
            a[4] = (short)bf16bits(xb.x); a[5] = (short)bf16bits(xb.y);
            a[6] = (short)bf16bits(xb.z); a[7] = (short)bf16bits(xb.w);
        }
        int kbase = kt * 32 + kg;
        #pragma unroll
        for (int t = 0; t < 5; ++t) {
            short8v b = *(const short8v*)&Wt[(t * 16 + jcol) * K + kbase];
            acc[t] = __builtin_amdgcn_mfma_f32_16x16x32_bf16(a, b, acc[t], 0, 0, 0);
        }
    }

    // C layout: col = l&15 (tile t -> col t*16+jcol), row = (l>>4)*4 + reg
    int rbase = rowbase + (l >> 4) * 4;
    #pragma unroll
    for (int t = 0; t < 4; ++t) {
        #pragma unroll
        for (int rr = 0; rr < 4; ++rr) {
            float v = acc[t][rr];
            float w = __shfl_xor(v, 1);
            int row = rbase + rr;
            if (!(l & 1) && row < N)
                hb_out[(size_t)row * 32 + t * 8 + (jcol >> 1)] = pack2bf(v, w);
        }
    }
    #pragma unroll
    for (int rr = 0; rr < 4; ++rr) {
        int row = rbase + rr;
        if (row < N) {
            if (jcol == 0) alpha_src[row] = acc[4][rr];
            if (jcol == 1) alpha_dst[row] = acc[4][rr];
        }
    }
}

// ---------------------------------------------------------------------------
// scatter_nt1: blocks [0,eb3) = bucket scatter (reservation via cursors);
// blocks [eb3, eb3+ntb) = NT layer-1. Independent work, one dispatch.
// ebuf entry = (dst&63)<<16 | src   (requires N <= 65536)
// ---------------------------------------------------------------------------
__global__ __launch_bounds__(256) void scatter_nt1(
    const int* __restrict__ src, const int* __restrict__ dst,
    const int* __restrict__ bucket_base, int* __restrict__ cursor0,
    unsigned* __restrict__ ebuf, int E, int eb3,
    const float* __restrict__ x, const unsigned short* __restrict__ Wt1,
    unsigned* __restrict__ hb_out,
    float* __restrict__ alpha_src, float* __restrict__ alpha_dst, int N) {
    int tid = threadIdx.x;
    if ((int)blockIdx.x >= eb3) {
        nt_body<128, false>(blockIdx.x - eb3, x, Wt1, hb_out,
                            alpha_src, alpha_dst, N, tid);
        return;
    }
    __shared__ int lhist[NBUK];
    __shared__ int lbase[NBUK];
    for (int s = tid; s < NBUK; s += 256) lhist[s] = 0;
    __syncthreads();
    int base = blockIdx.x * EPB;
    int bkt[16], rank[16];
    unsigned pack[16];
    #pragma unroll
    for (int i = 0; i < 16; ++i) {
        int e = base + i * 256 + tid;
        bkt[i] = -1;
        if (e < E) {
            int d = dst[e], s = src[e];
            bkt[i]  = d >> 6;
            pack[i] = ((unsigned)(d & 63) << 16) | (unsigned)s;
            rank[i] = atomicAdd(&lhist[bkt[i]], 1);
        }
    }
    __syncthreads();
    for (int s = tid; s < NBUK; s += 256) {
        int c = lhist[s];
        if (c) lbase[s] = bucket_base[s] + atomicAdd(&cursor0[s], c);
    }
    __syncthreads();
    #pragma unroll
    for (int i = 0; i < 16; ++i)
        if (bkt[i] >= 0) ebuf[lbase[bkt[i]] + rank[i]] = pack[i];
}

// ---------------------------------------------------------------------------
// bucket_build: block per bucket (64 nodes, ~1.5K edges): deg histogram ->
// 64-scan -> row_ptr + csr16 scatter into the bucket's contiguous run.
// ---------------------------------------------------------------------------
__global__ __launch_bounds__(256) void bucket_build(
    const unsigned* __restrict__ ebuf, const int* __restrict__ bucket_base,
    int* __restrict__ row_ptr, unsigned short* __restrict__ csr16,
    int N, int E) {
    __shared__ int deg[64];
    __shared__ int cur[64];
    __shared__ int tmp[256];
    int b = blockIdx.x, tid = threadIdx.x;
    int ebase = bucket_base[b], eend = bucket_base[b + 1];
    if (tid < 64) deg[tid] = 0;
    __syncthreads();
    for (int e = ebase + tid; e < eend; e += 256)
        atomicAdd(&deg[ebuf[e] >> 16], 1);
    __syncthreads();
    int v = (tid < 64) ? deg[tid] : 0;
    tmp[tid] = v;
    __syncthreads();
    for (int off = 1; off < 64; off <<= 1) {
        int t = (tid >= off) ? tmp[tid - off] : 0;
        __syncthreads();
        tmp[tid] += t;
        __syncthreads();
    }
    int excl = tmp[tid] - v;
    int node = b * 64 + tid;
    if (tid < 64 && node < N) row_ptr[node] = ebase + excl;
    if (b == 0 && tid == 0) row_ptr[N] = E;
    if (tid < 64) cur[tid] = excl;
    __syncthreads();
    for (int e = ebase + tid; e < eend; e += 256) {
        unsigned pk = ebuf[e];
        int r = atomicAdd(&cur[pk >> 16], 1);
        csr16[ebase + r] = (unsigned short)(pk & 0xFFFFu);
    }
}

// ---------------------------------------------------------------------------
// Aggregation: wave per dst node. Direct-exp softmax (logits O(10), fp32-exp
// safe; ratio identical to max-subtracted). Logit phase lane = edge.
// Gather phase: (s,p) staged once per chunk into wave-private LDS as float2
// (even edges slots 0..31, odd 32..63) -> each half-wave reads its edge
// group as consecutive pairs via b128 (same-addr broadcast, conflict-free).
// Half-wave per edge, lane = u32 (2 bf16 feats); 32-edge groups = 16 gathers
// in flight; lanes >= cnt stage p=0,s=0 (guard-free).
// ---------------------------------------------------------------------------
template <bool OUTBF16>
__global__ __launch_bounds__(256) void aggregate(
    const int* __restrict__ row_ptr, const unsigned short* __restrict__ csr16,
    const float* __restrict__ alpha_src, const float* __restrict__ alpha_dst,
    const unsigned* __restrict__ hb,    // [N][32] packed bf16x2
    const float* __restrict__ bias,     // [64]
    void* __restrict__ out_,            // fp32 [N][64] or packed bf16 [N][32]
    int N) {
    __shared__ float2 spbuf[4][64];
    int wid = threadIdx.x >> 6, lane = threadIdx.x & 63;
    int node = blockIdx.x * 4 + wid;
    if (node >= N) return;

    int beg = row_ptr[node], end = row_ptr[node + 1];
    float adst = alpha_dst[node];
    int half = lane >> 5, sub = lane & 31;
    float2* __restrict__ mysp = spbuf[wid];
    int wslot = (lane & 1) * 32 + (lane >> 1);
    int rbase = half * 32;

    float dL = 0.f;
    float aA[4] = {0.f, 0.f, 0.f, 0.f};
    float aB[4] = {0.f, 0.f, 0.f, 0.f};

    for (int c = beg; c < end; c += 64) {
        int cnt = end - c;
        cnt = (cnt < 64) ? cnt : 64;

        int s = 0;
        float p = 0.f;
        if (lane < cnt) {
            s = csr16[c + lane];
            float t = alpha_src[s] + adst;
            t = (t > 0.f) ? t : NEG_SLOPE * t;
            p = __expf(fminf(t, 60.f));
            dL += p;
        }
        // stage (s,p); wave-private region, DS ops in-order per wave -> no barrier
        mysp[wslot] = make_float2(__int_as_float(s), p);

        // 32-edge groups: 16 independent gathers in flight per lane
        for (int j = 0; j < cnt; j += 32) {
            int sl = rbase + (j >> 1);
            int   sv[16];
            float pv[16];
            unsigned uv[16];
            #pragma unroll
            for (int g = 0; g < 8; ++g) {
                float4 q = *(const float4*)&mysp[sl + 2 * g];
                sv[2 * g]     = __float_as_int(q.x);
                pv[2 * g]     = q.y;
                sv[2 * g + 1] = __float_as_int(q.z);
                pv[2 * g + 1] = q.w;
            }
            #pragma unroll
            for (int i = 0; i < 16; ++i)
                uv[i] = hb[(size_t)sv[i] * 32 + sub];
            #pragma unroll
            for (int i = 0; i < 16; ++i) {
                aA[i & 3] = fmaf(pv[i], blo(uv[i]), aA[i & 3]);
                aB[i & 3] = fmaf(pv[i], bhi(uv[i]), aB[i & 3]);
            }
        }
    }
    float denom = dL;
    #pragma unroll
    for (int off = 32; off; off >>= 1) denom += __shfl_xor(denom, off);

    float accA = (aA[0] + aA[1]) + (aA[2] + aA[3]);
    float accB = (aB[0] + aB[1]) + (aB[2] + aB[3]);
    accA += __shfl_xor(accA, 32);
    accB += __shfl_xor(accB, 32);
    int srcl = lane >> 1;
    float vA = __shfl(accA, srcl);
    float vB = __shfl(accB, srcl);
    float val = (lane & 1) ? vB : vA;
    float r = (denom > 0.f) ? (val / denom) : 0.f;
    float fv = tanhf(r + bias[lane]);

    if constexpr (OUTBF16) {
        float fw = __shfl_xor(fv, 1);
        if (!(lane & 1))
            ((unsigned*)out_)[(size_t)node * 32 + (lane >> 1)] = pack2bf(fv, fw);
    } else {
        ((float*)out_)[(size_t)node * 64 + lane] = fv;
    }
}

// ---------------------------------------------------------------------------
// Standalone NT (layer 2).
// ---------------------------------------------------------------------------
__global__ __launch_bounds__(256) void nt2(
    const unsigned short* __restrict__ x, const unsigned short* __restrict__ Wt,
    unsigned* __restrict__ hb_out,
    float* __restrict__ alpha_src, float* __restrict__ alpha_dst, int N) {
    nt_body<64, true>(blockIdx.x, x, Wt, hb_out, alpha_src, alpha_dst,
                      N, threadIdx.x);
}

// ---------------------------------------------------------------------------
extern "C" void kernel_launch(void* const* d_in, const int* in_sizes, int n_in,
                              void* d_out, int out_size, void* d_ws, size_t ws_size,
                              hipStream_t stream) {
    const float* x      = (const float*)d_in[0];
    const int*   src    = (const int*)  d_in[1];
    const int*   dst    = (const int*)  d_in[2];
    const float* W1_src = (const float*)d_in[3];
    const float* W1_dst = (const float*)d_in[4];
    const float* a1_src = (const float*)d_in[5];
    const float* a1_dst = (const float*)d_in[6];
    const float* b1     = (const float*)d_in[7];
    const float* W2_src = (const float*)d_in[8];
    const float* W2_dst = (const float*)d_in[9];
    const float* a2_src = (const float*)d_in[10];
    const float* a2_dst = (const float*)d_in[11];
    const float* b2     = (const float*)d_in[12];
    float* out = (float*)d_out;

    const int N = in_sizes[0] / 128;
    const int E = in_sizes[1];
    const int nbuk = (N + 63) / 64;          // occupied buckets (782)

    char* ws = (char*)d_ws;
    size_t off = 0;
    auto alloc = [&](size_t bytes) {
        void* p = ws + off;
        off += (bytes + 255) & ~(size_t)255;
        return p;
    };
    unsigned* hbuf1  = (unsigned*)alloc((size_t)N * 32 * 4);  // h layer-1 (bf16x2)
    unsigned* h1buf  = (unsigned*)alloc((size_t)N * 32 * 4);  // tanh'd agg1 (bf16x2)
    unsigned* hbuf2  = (unsigned*)alloc((size_t)N * 32 * 4);  // h layer-2 (bf16x2)
    float* alpha_s1  = (float*)alloc((size_t)N * 4);
    float* alpha_d1  = (float*)alloc((size_t)N * 4);
    float* alpha_s2  = (float*)alloc((size_t)N * 4);
    float* alpha_d2  = (float*)alloc((size_t)N * 4);
    int*   row_ptr   = (int*)  alloc((size_t)(N + 1) * 4);
    unsigned short* csr16 = (unsigned short*)alloc((size_t)E * 2);
    int*   partials  = (int*)  alloc((size_t)NHB * NBUK * 4);
    int*   bucket_base = (int*)alloc((NBUK + 1) * 4);
    int*   cursor0   = (int*)  alloc(NBUK * 4);
    unsigned short* Wt1 = (unsigned short*)alloc(80 * 128 * 2);
    unsigned short* Wt2 = (unsigned short*)alloc(80 * 64 * 2);
    unsigned* ebuf   = (unsigned*)alloc((size_t)E * 4);
    (void)ws_size;

    const int eb3  = (E + EPB - 1) / EPB;
    const int nwb  = (N + 3) / 4;            // wave-per-node blocks
    const int ntb  = (N + 63) / 64;          // NT: 4 tiles of 16 rows / block

    // 1) prep: 1024-bucket hist partials + Wt1 + Wt2
    prep<<<NHB + 2, 256, 0, stream>>>(dst, partials, E,
                                      W1_src, a1_src, W1_dst, a1_dst,
                                      W2_src, a2_src, W2_dst, a2_dst,
                                      Wt1, Wt2);
    // 2) scan 1024 buckets + zero cursors
    scan1024<<<1, 256, 0, stream>>>(partials, bucket_base, cursor0);
    // 3) bucket scatter || NT layer-1
    scatter_nt1<<<eb3 + ntb, 256, 0, stream>>>(
        src, dst, bucket_base, cursor0, ebuf, E, eb3,
        x, Wt1, hbuf1, alpha_s1, alpha_d1, N);
    // 4) per-bucket CSR finalize (782 blocks)
    bucket_build<<<nbuk, 256, 0, stream>>>(ebuf, bucket_base, row_ptr, csr16, N, E);
    // 5) agg layer-1 -> h1 (bf16 rows)
    aggregate<true><<<nwb, 256, 0, stream>>>(row_ptr, csr16, alpha_s1, alpha_d1,
                                             hbuf1, b1, h1buf, N);
    // 6) NT layer-2
    nt2<<<ntb, 256, 0, stream>>>((const unsigned short*)h1buf, Wt2,
                                 hbuf2, alpha_s2, alpha_d2, N);
    // 7) agg layer-2 -> out
    aggregate<false><<<nwb, 256, 0, stream>>>(row_ptr, csr16, alpha_s2, alpha_d2,
                                              hbuf2, b2, out, N);
}

// Round 18
// 128.522 us; speedup vs baseline: 1.0330x; 1.0330x over previous
//
#include <hip/hip_runtime.h>
#include <hip/hip_bf16.h>

#define NEG_SLOPE 0.2f
#define EPB 4096    // edges per block in bucket_scatter (256 thr x 16)
#define NHB 64      // hist blocks
#define NBUK 1024   // bucket slots (bucket = node >> 6, 64 nodes/bucket)

typedef __attribute__((ext_vector_type(8))) short short8v;   // 8 bf16 bit-patterns
typedef __attribute__((ext_vector_type(4))) float f32x4;

__device__ inline float blo(unsigned u) { return __uint_as_float(u << 16); }
__device__ inline float bhi(unsigned u) { return __uint_as_float(u & 0xffff0000u); }
__device__ inline unsigned short bf16bits(float f) {
    __hip_bfloat16 b = __float2bfloat16(f);
    return *(unsigned short*)&b;
}
__device__ inline unsigned pack2bf(float e, float o) {
    return ((unsigned)bf16bits(o) << 16) | (unsigned)bf16bits(e);
}

// ---------------------------------------------------------------------------
// Augmented transposed weights Wt[80][K] bf16:
// j<64 -> W_src[k][j]; j=64 -> W_src@a_src; j=65 -> W_dst@a_dst; 66..79 -> 0.
// ---------------------------------------------------------------------------
template <int K>
__device__ inline void build_wt(unsigned short* __restrict__ Wt,
                                const float* __restrict__ W_src,
                                const float* __restrict__ a_src,
                                const float* __restrict__ W_dst,
                                const float* __restrict__ a_dst, int tid) {
    for (int i = tid; i < 64 * K; i += 256) {
        int k = i >> 6, j = i & 63;
        Wt[j * K + k] = bf16bits(W_src[i]);
    }
    for (int i = tid; i < 2 * K; i += 256) {
        int which = (i >= K) ? 1 : 0;
        int k = i - which * K;
        const float* Wr = (which ? W_dst : W_src) + k * 64;
        const float* av = which ? a_dst : a_src;
        float s = 0.f;
        #pragma unroll
        for (int j = 0; j < 64; ++j) s += Wr[j] * av[j];
        Wt[(64 + which) * K + k] = bf16bits(s);
    }
    for (int i = tid; i < 14 * K; i += 256) Wt[66 * K + i] = 0;
}

// ---------------------------------------------------------------------------
// prep: blocks 0..NHB-1 = 1024-bucket histogram partials; NHB = Wt1; NHB+1 = Wt2.
// ---------------------------------------------------------------------------
__global__ __launch_bounds__(256) void prep(
    const int* __restrict__ dst, int* __restrict__ partials, int E,
    const float* __restrict__ W1_src, const float* __restrict__ a1_src,
    const float* __restrict__ W1_dst, const float* __restrict__ a1_dst,
    const float* __restrict__ W2_src, const float* __restrict__ a2_src,
    const float* __restrict__ W2_dst, const float* __restrict__ a2_dst,
    unsigned short* __restrict__ Wt1, unsigned short* __restrict__ Wt2) {
    __shared__ int lh[NBUK];
    int tid = threadIdx.x, b = blockIdx.x;
    if (b < NHB) {
        for (int s = tid; s < NBUK; s += 256) lh[s] = 0;
        __syncthreads();
        for (int e = b * 256 + tid; e < E; e += NHB * 256)
            atomicAdd(&lh[dst[e] >> 6], 1);
        __syncthreads();
        for (int s = tid; s < NBUK; s += 256)
            partials[b * NBUK + s] = lh[s];
    } else if (b == NHB) {
        build_wt<128>(Wt1, W1_src, a1_src, W1_dst, a1_dst, tid);
    } else {
        build_wt<64>(Wt2, W2_src, a2_src, W2_dst, a2_dst, tid);
    }
}

// ---------------------------------------------------------------------------
// scan1024 (1 block): reduce hist partials -> exclusive scan -> bucket_base;
// zero the cursors. Thread owns 4 consecutive slots (int4 loads).
// ---------------------------------------------------------------------------
__global__ __launch_bounds__(256) void scan1024(const int* __restrict__ partials,
                                                int* __restrict__ bucket_base,
                                                int* __restrict__ cursor0) {
    __shared__ int tsum[256];
    int tid = threadIdx.x;
    int4 v = make_int4(0, 0, 0, 0);
    for (int b = 0; b < NHB; ++b) {
        int4 p = *(const int4*)&partials[b * NBUK + 4 * tid];
        v.x += p.x; v.y += p.y; v.z += p.z; v.w += p.w;
    }
    int t = v.x + v.y + v.z + v.w;
    tsum[tid] = t;
    __syncthreads();
    for (int off = 1; off < 256; off <<= 1) {
        int u = (tid >= off) ? tsum[tid - off] : 0;
        __syncthreads();
        tsum[tid] += u;
        __syncthreads();
    }
    int base = tsum[tid] - t;    // exclusive across thread groups
    bucket_base[4 * tid + 0] = base;
    bucket_base[4 * tid + 1] = base + v.x;
    bucket_base[4 * tid + 2] = base + v.x + v.y;
    bucket_base[4 * tid + 3] = base + v.x + v.y + v.z;
    if (tid == 255) bucket_base[NBUK] = tsum[255];   // == E
    *(int4*)&cursor0[4 * tid] = make_int4(0, 0, 0, 0);
}

// ---------------------------------------------------------------------------
// NT body (register-resident, no LDS): wave = 16-row x 80-col tile.
//   h = x@W_src (packed bf16 [N][32]), alpha_src = col 64, alpha_dst = col 65.
// ---------------------------------------------------------------------------
template <int K, bool INBF16>
__device__ inline void nt_body(int nb, const void* __restrict__ x_,
                               const unsigned short* __restrict__ Wt,
                               unsigned* __restrict__ hb_out,
                               float* __restrict__ alpha_src,
                               float* __restrict__ alpha_dst, int N, int tid) {
    int wid = tid >> 6, l = tid & 63;
    int rowbase = (nb * 4 + wid) * 16;
    if (rowbase >= N) return;
    int jcol = l & 15, kg = (l >> 4) * 8;

    int r = rowbase + jcol;
    if (r >= N) r = N - 1;           // clamp; stores guarded
    const float*          xr32 = (const float*)x_ + (size_t)r * K + kg;
    const unsigned short* xr16 = (const unsigned short*)x_ + (size_t)r * K + kg;

    f32x4 acc[5];
    #pragma unroll
    for (int t = 0; t < 5; ++t) acc[t] = (f32x4){0.f, 0.f, 0.f, 0.f};

    #pragma unroll
    for (int kt = 0; kt < K / 32; ++kt) {
        short8v a;
        if constexpr (INBF16) {
            a = *(const short8v*)(xr16 + kt * 32);
        } else {
            float4 xa = *(const float4*)(xr32 + kt * 32);
            float4 xb = *(const float4*)(xr32 + kt * 32 + 4);
            a[0] = (short)bf16bits(xa.x); a[1] = (short)bf16bits(xa.y);
            a[2] = (short)bf16bits(xa.z); a[3] = (short)bf16bits(xa.w);
            a[4] = (short)bf16bits(xb.x); a[5] = (short)bf16bits(xb.y);
            a[6] = (short)bf16bits(xb.z); a[7] = (short)bf16bits(xb.w);
        }
        int kbase = kt * 32 + kg;
        #pragma unroll
        for (int t = 0; t < 5; ++t) {
            short8v b = *(const short8v*)&Wt[(t * 16 + jcol) * K + kbase];
            acc[t] = __builtin_amdgcn_mfma_f32_16x16x32_bf16(a, b, acc[t], 0, 0, 0);
        }
    }

    // C layout: col = l&15 (tile t -> col t*16+jcol), row = (l>>4)*4 + reg
    int rbase = rowbase + (l >> 4) * 4;
    #pragma unroll
    for (int t = 0; t < 4; ++t) {
        #pragma unroll
        for (int rr = 0; rr < 4; ++rr) {
            float v = acc[t][rr];
            float w = __shfl_xor(v, 1);
            int row = rbase + rr;
            if (!(l & 1) && row < N)
                hb_out[(size_t)row * 32 + t * 8 + (jcol >> 1)] = pack2bf(v, w);
        }
    }
    #pragma unroll
    for (int rr = 0; rr < 4; ++rr) {
        int row = rbase + rr;
        if (row < N) {
            if (jcol == 0) alpha_src[row] = acc[4][rr];
            if (jcol == 1) alpha_dst[row] = acc[4][rr];
        }
    }
}

// ---------------------------------------------------------------------------
// scatter_nt1: blocks [0,eb3) = bucket scatter (reservation via cursors);
// blocks [eb3, eb3+ntb) = NT layer-1. Independent work, one dispatch.
// ebuf entry = (dst&63)<<16 | src   (requires N <= 65536)
// ---------------------------------------------------------------------------
__global__ __launch_bounds__(256) void scatter_nt1(
    const int* __restrict__ src, const int* __restrict__ dst,
    const int* __restrict__ bucket_base, int* __restrict__ cursor0,
    unsigned* __restrict__ ebuf, int E, int eb3,
    const float* __restrict__ x, const unsigned short* __restrict__ Wt1,
    unsigned* __restrict__ hb_out,
    float* __restrict__ alpha_src, float* __restrict__ alpha_dst, int N) {
    int tid = threadIdx.x;
    if ((int)blockIdx.x >= eb3) {
        nt_body<128, false>(blockIdx.x - eb3, x, Wt1, hb_out,
                            alpha_src, alpha_dst, N, tid);
        return;
    }
    __shared__ int lhist[NBUK];
    __shared__ int lbase[NBUK];
    for (int s = tid; s < NBUK; s += 256) lhist[s] = 0;
    __syncthreads();
    int base = blockIdx.x * EPB;
    int bkt[16], rank[16];
    unsigned pack[16];
    #pragma unroll
    for (int i = 0; i < 16; ++i) {
        int e = base + i * 256 + tid;
        bkt[i] = -1;
        if (e < E) {
            int d = dst[e], s = src[e];
            bkt[i]  = d >> 6;
            pack[i] = ((unsigned)(d & 63) << 16) | (unsigned)s;
            rank[i] = atomicAdd(&lhist[bkt[i]], 1);
        }
    }
    __syncthreads();
    for (int s = tid; s < NBUK; s += 256) {
        int c = lhist[s];
        if (c) lbase[s] = bucket_base[s] + atomicAdd(&cursor0[s], c);
    }
    __syncthreads();
    #pragma unroll
    for (int i = 0; i < 16; ++i)
        if (bkt[i] >= 0) ebuf[lbase[bkt[i]] + rank[i]] = pack[i];
}

// ---------------------------------------------------------------------------
// bucket_build: block per bucket (64 nodes, ~1.5K edges): deg histogram ->
// 64-scan -> row_ptr + csr16 scatter into the bucket's contiguous run.
// ---------------------------------------------------------------------------
__global__ __launch_bounds__(256) void bucket_build(
    const unsigned* __restrict__ ebuf, const int* __restrict__ bucket_base,
    int* __restrict__ row_ptr, unsigned short* __restrict__ csr16,
    int N, int E) {
    __shared__ int deg[64];
    __shared__ int cur[64];
    __shared__ int tmp[256];
    int b = blockIdx.x, tid = threadIdx.x;
    int ebase = bucket_base[b], eend = bucket_base[b + 1];
    if (tid < 64) deg[tid] = 0;
    __syncthreads();
    for (int e = ebase + tid; e < eend; e += 256)
        atomicAdd(&deg[ebuf[e] >> 16], 1);
    __syncthreads();
    int v = (tid < 64) ? deg[tid] : 0;
    tmp[tid] = v;
    __syncthreads();
    for (int off = 1; off < 64; off <<= 1) {
        int t = (tid >= off) ? tmp[tid - off] : 0;
        __syncthreads();
        tmp[tid] += t;
        __syncthreads();
    }
    int excl = tmp[tid] - v;
    int node = b * 64 + tid;
    if (tid < 64 && node < N) row_ptr[node] = ebase + excl;
    if (b == 0 && tid == 0) row_ptr[N] = E;
    if (tid < 64) cur[tid] = excl;
    __syncthreads();
    for (int e = ebase + tid; e < eend; e += 256) {
        unsigned pk = ebuf[e];
        int r = atomicAdd(&cur[pk >> 16], 1);
        csr16[ebase + r] = (unsigned short)(pk & 0xFFFFu);
    }
}

// ---------------------------------------------------------------------------
// Aggregation: wave per dst node. Direct-exp softmax (logits O(10), fp32-exp
// safe; ratio identical to max-subtracted). Logit phase lane = edge.
// Gather phase: (s,p) staged once per chunk into wave-private LDS as float2
// (even edges slots 0..31, odd 32..63) -> each half-wave reads its 8-edge
// group as 4x consecutive pairs via b128 (same-addr broadcast, conflict-free).
// Half-wave per edge, lane = u32 (2 bf16 feats); 16-edge groups = 8 gathers
// in flight; lanes >= cnt stage p=0,s=0 (guard-free).
// ---------------------------------------------------------------------------
template <bool OUTBF16>
__global__ __launch_bounds__(256) void aggregate(
    const int* __restrict__ row_ptr, const unsigned short* __restrict__ csr16,
    const float* __restrict__ alpha_src, const float* __restrict__ alpha_dst,
    const unsigned* __restrict__ hb,    // [N][32] packed bf16x2
    const float* __restrict__ bias,     // [64]
    void* __restrict__ out_,            // fp32 [N][64] or packed bf16 [N][32]
    int N) {
    __shared__ float2 spbuf[4][64];
    int wid = threadIdx.x >> 6, lane = threadIdx.x & 63;
    int node = blockIdx.x * 4 + wid;
    if (node >= N) return;

    int beg = row_ptr[node], end = row_ptr[node + 1];
    float adst = alpha_dst[node];
    int half = lane >> 5, sub = lane & 31;
    float2* __restrict__ mysp = spbuf[wid];
    int wslot = (lane & 1) * 32 + (lane >> 1);
    int rbase = half * 32;

    float dL = 0.f;
    float aA[4] = {0.f, 0.f, 0.f, 0.f};
    float aB[4] = {0.f, 0.f, 0.f, 0.f};

    for (int c = beg; c < end; c += 64) {
        int cnt = end - c;
        cnt = (cnt < 64) ? cnt : 64;

        int s = 0;
        float p = 0.f;
        if (lane < cnt) {
            s = csr16[c + lane];
            float t = alpha_src[s] + adst;
            t = (t > 0.f) ? t : NEG_SLOPE * t;
            p = __expf(fminf(t, 60.f));
            dL += p;
        }
        // stage (s,p); wave-private region, DS ops in-order per wave -> no barrier
        mysp[wslot] = make_float2(__int_as_float(s), p);

        for (int j = 0; j < cnt; j += 16) {
            int sl = rbase + (j >> 1);
            float4 q0 = *(const float4*)&mysp[sl];
            float4 q1 = *(const float4*)&mysp[sl + 2];
            float4 q2 = *(const float4*)&mysp[sl + 4];
            float4 q3 = *(const float4*)&mysp[sl + 6];
            int   sv[8] = {__float_as_int(q0.x), __float_as_int(q0.z),
                           __float_as_int(q1.x), __float_as_int(q1.z),
                           __float_as_int(q2.x), __float_as_int(q2.z),
                           __float_as_int(q3.x), __float_as_int(q3.z)};
            float pv[8] = {q0.y, q0.w, q1.y, q1.w, q2.y, q2.w, q3.y, q3.w};
            unsigned uv[8];
            #pragma unroll
            for (int i = 0; i < 8; ++i)
                uv[i] = hb[(size_t)sv[i] * 32 + sub];
            #pragma unroll
            for (int i = 0; i < 8; ++i) {
                aA[i & 3] = fmaf(pv[i], blo(uv[i]), aA[i & 3]);
                aB[i & 3] = fmaf(pv[i], bhi(uv[i]), aB[i & 3]);
            }
        }
    }
    float denom = dL;
    #pragma unroll
    for (int off = 32; off; off >>= 1) denom += __shfl_xor(denom, off);

    float accA = (aA[0] + aA[1]) + (aA[2] + aA[3]);
    float accB = (aB[0] + aB[1]) + (aB[2] + aB[3]);
    accA += __shfl_xor(accA, 32);
    accB += __shfl_xor(accB, 32);
    int srcl = lane >> 1;
    float vA = __shfl(accA, srcl);
    float vB = __shfl(accB, srcl);
    float val = (lane & 1) ? vB : vA;
    float r = (denom > 0.f) ? (val / denom) : 0.f;
    float fv = tanhf(r + bias[lane]);

    if constexpr (OUTBF16) {
        float fw = __shfl_xor(fv, 1);
        if (!(lane & 1))
            ((unsigned*)out_)[(size_t)node * 32 + (lane >> 1)] = pack2bf(fv, fw);
    } else {
        ((float*)out_)[(size_t)node * 64 + lane] = fv;
    }
}

// ---------------------------------------------------------------------------
// Standalone NT (layer 2).
// ---------------------------------------------------------------------------
__global__ __launch_bounds__(256) void nt2(
    const unsigned short* __restrict__ x, const unsigned short* __restrict__ Wt,
    unsigned* __restrict__ hb_out,
    float* __restrict__ alpha_src, float* __restrict__ alpha_dst, int N) {
    nt_body<64, true>(blockIdx.x, x, Wt, hb_out, alpha_src, alpha_dst,
                      N, threadIdx.x);
}

// ---------------------------------------------------------------------------
extern "C" void kernel_launch(void* const* d_in, const int* in_sizes, int n_in,
                              void* d_out, int out_size, void* d_ws, size_t ws_size,
                              hipStream_t stream) {
    const float* x      = (const float*)d_in[0];
    const int*   src    = (const int*)  d_in[1];
    const int*   dst    = (const int*)  d_in[2];
    const float* W1_src = (const float*)d_in[3];
    const float* W1_dst = (const float*)d_in[4];
    const float* a1_src = (const float*)d_in[5];
    const float* a1_dst = (const float*)d_in[6];
    const float* b1     = (const float*)d_in[7];
    const float* W2_src = (const float*)d_in[8];
    const float* W2_dst = (const float*)d_in[9];
    const float* a2_src = (const float*)d_in[10];
    const float* a2_dst = (const float*)d_in[11];
    const float* b2     = (const float*)d_in[12];
    float* out = (float*)d_out;

    const int N = in_sizes[0] / 128;
    const int E = in_sizes[1];
    const int nbuk = (N + 63) / 64;          // occupied buckets (782)

    char* ws = (char*)d_ws;
    size_t off = 0;
    auto alloc = [&](size_t bytes) {
        void* p = ws + off;
        off += (bytes + 255) & ~(size_t)255;
        return p;
    };
    unsigned* hbuf1  = (unsigned*)alloc((size_t)N * 32 * 4);  // h layer-1 (bf16x2)
    unsigned* h1buf  = (unsigned*)alloc((size_t)N * 32 * 4);  // tanh'd agg1 (bf16x2)
    unsigned* hbuf2  = (unsigned*)alloc((size_t)N * 32 * 4);  // h layer-2 (bf16x2)
    float* alpha_s1  = (float*)alloc((size_t)N * 4);
    float* alpha_d1  = (float*)alloc((size_t)N * 4);
    float* alpha_s2  = (float*)alloc((size_t)N * 4);
    float* alpha_d2  = (float*)alloc((size_t)N * 4);
    int*   row_ptr   = (int*)  alloc((size_t)(N + 1) * 4);
    unsigned short* csr16 = (unsigned short*)alloc((size_t)E * 2);
    int*   partials  = (int*)  alloc((size_t)NHB * NBUK * 4);
    int*   bucket_base = (int*)alloc((NBUK + 1) * 4);
    int*   cursor0   = (int*)  alloc(NBUK * 4);
    unsigned short* Wt1 = (unsigned short*)alloc(80 * 128 * 2);
    unsigned short* Wt2 = (unsigned short*)alloc(80 * 64 * 2);
    unsigned* ebuf   = (unsigned*)alloc((size_t)E * 4);
    (void)ws_size;

    const int eb3  = (E + EPB - 1) / EPB;
    const int nwb  = (N + 3) / 4;            // wave-per-node blocks
    const int ntb  = (N + 63) / 64;          // NT: 4 tiles of 16 rows / block

    // 1) prep: 1024-bucket hist partials + Wt1 + Wt2
    prep<<<NHB + 2, 256, 0, stream>>>(dst, partials, E,
                                      W1_src, a1_src, W1_dst, a1_dst,
                                      W2_src, a2_src, W2_dst, a2_dst,
                                      Wt1, Wt2);
    // 2) scan 1024 buckets + zero cursors
    scan1024<<<1, 256, 0, stream>>>(partials, bucket_base, cursor0);
    // 3) bucket scatter || NT layer-1
    scatter_nt1<<<eb3 + ntb, 256, 0, stream>>>(
        src, dst, bucket_base, cursor0, ebuf, E, eb3,
        x, Wt1, hbuf1, alpha_s1, alpha_d1, N);
    // 4) per-bucket CSR finalize (782 blocks)
    bucket_build<<<nbuk, 256, 0, stream>>>(ebuf, bucket_base, row_ptr, csr16, N, E);
    // 5) agg layer-1 -> h1 (bf16 rows)
    aggregate<true><<<nwb, 256, 0, stream>>>(row_ptr, csr16, alpha_s1, alpha_d1,
                                             hbuf1, b1, h1buf, N);
    // 6) NT layer-2
    nt2<<<ntb, 256, 0, stream>>>((const unsigned short*)h1buf, Wt2,
                                 hbuf2, alpha_s2, alpha_d2, N);
    // 7) agg layer-2 -> out
    aggregate<false><<<nwb, 256, 0, stream>>>(row_ptr, csr16, alpha_s2, alpha_d2,
                                              hbuf2, b2, out, N);
}